// Round 1
// baseline (1809.745 us; speedup 1.0000x reference)
//
#include <hip/hip_runtime.h>
#include <math.h>

#define B_ 4
#define N_ 2048
#define C_ 256
#define KMAX_ 1024
#define KU_ 171
#define ITERS_ 3
#define H_ 4
#define EPS_ 1e-8f
#define SIGF_ 0.03f
#define JIT_ 1e-6f
#define LOGKMAX_ 6.93147180559945f

// ---------------- workspace layout (float offsets) ----------------
#define WS_CNT 0          // 4
#define WS_MUS 4          // 12
#define WS_MOS 16         // 24 (6 per batch: 00,01,02,11,12,22)
#define WS_SGS 40         // 36
#define WS_SSUM 128       // 1024
#define WS_STATS_BYTES (1152*4)
#define WS_MEAN 1152      // 12
#define WS_STD 1164       // 12
#define WS_SIGAVG 1176    // 36
#define WS_IDXI 1216      // 684 ints (pad to 1920)
#define WS_KSEM 1920                  // B*N*C = 2097152
#define WS_QSEM (WS_KSEM+2097152)     // 175104
#define WS_OCC  (WS_QSEM+175104)      // 684 (pad 704)
#define WS_SLOTIN (WS_OCC+704)        // 175104
#define WS_GI (WS_SLOTIN+175104)      // 525312
#define WS_GH (WS_GI+525312)          // 525312
#define WS_XM (WS_GH+525312)          // 175104
#define WS_HID (WS_XM+175104)         // 700416
#define WS_ATA (WS_HID+700416)        // 116964

// ---------------- output layout (float offsets) ----------------
#define O_A 0
#define O_SLOTS 1400832
#define O_MUK   1575936
#define O_SIGK  1577988
#define O_IDX   1584144
#define O_KL    1584828
#define O_ENT   1584829
#define O_OCC   1584830
#define O_COL   1584831
#define O_TOT   1584832

__device__ __forceinline__ float blk_red(float v, float* red, int t) {
  red[t] = v; __syncthreads();
  #pragma unroll
  for (int s = 128; s > 0; s >>= 1) {
    if (t < s) red[t] += red[t + s];
    __syncthreads();
  }
  float r = red[0]; __syncthreads();
  return r;
}

// ---- partial batch stats: cnt, sum(m*mu), sum(m*mu mu^T), sum(m*Sigma), sum(m*s) ----
__global__ __launch_bounds__(256) void k_stats(const float* __restrict__ s,
    const float* __restrict__ mu, const float* __restrict__ Sigma,
    const float* __restrict__ mask, float* __restrict__ ws) {
  int blk = blockIdx.x; int b = blk / 8; int nc = blk % 8; int t = threadIdx.x;
  int n = nc * 256 + t;
  float m = mask[b * N_ + n];
  const float* mun = mu + ((size_t)(b * N_ + n)) * 3;
  float m0 = mun[0], m1v = mun[1], m2 = mun[2];
  const float* sgn = Sigma + ((size_t)(b * N_ + n)) * 9;
  float sg[9];
  #pragma unroll
  for (int j = 0; j < 9; j++) sg[j] = sgn[j];
  __shared__ float red[256];
  float v;
  v = blk_red(m, red, t);           if (t == 0) atomicAdd(ws + WS_CNT + b, v);
  v = blk_red(m * m0, red, t);      if (t == 0) atomicAdd(ws + WS_MUS + b * 3 + 0, v);
  v = blk_red(m * m1v, red, t);     if (t == 0) atomicAdd(ws + WS_MUS + b * 3 + 1, v);
  v = blk_red(m * m2, red, t);      if (t == 0) atomicAdd(ws + WS_MUS + b * 3 + 2, v);
  v = blk_red(m * m0 * m0, red, t); if (t == 0) atomicAdd(ws + WS_MOS + b * 6 + 0, v);
  v = blk_red(m * m0 * m1v, red, t);if (t == 0) atomicAdd(ws + WS_MOS + b * 6 + 1, v);
  v = blk_red(m * m0 * m2, red, t); if (t == 0) atomicAdd(ws + WS_MOS + b * 6 + 2, v);
  v = blk_red(m * m1v * m1v, red, t);if (t == 0) atomicAdd(ws + WS_MOS + b * 6 + 3, v);
  v = blk_red(m * m1v * m2, red, t);if (t == 0) atomicAdd(ws + WS_MOS + b * 6 + 4, v);
  v = blk_red(m * m2 * m2, red, t); if (t == 0) atomicAdd(ws + WS_MOS + b * 6 + 5, v);
  #pragma unroll
  for (int j = 0; j < 9; j++) {
    v = blk_red(m * sg[j], red, t);
    if (t == 0) atomicAdd(ws + WS_SGS + b * 9 + j, v);
  }
  // s-column sums: thread t owns column c=t over this block's 256 rows
  const float* sb = s + ((size_t)b * N_ + nc * 256) * C_;
  const float* mk = mask + b * N_ + nc * 256;
  float sa = 0.f;
  for (int nn = 0; nn < 256; nn++) sa += mk[nn] * sb[(size_t)nn * C_ + t];
  atomicAdd(ws + WS_SSUM + b * C_ + t, sa);
}

// ---- finalize mean/std/sigavg ----
__global__ __launch_bounds__(64) void k_fin(float* __restrict__ ws) {
  int t = threadIdx.x;
  if (t < B_) {
    int b = t;
    float cnt = fmaxf(ws[WS_CNT + b], EPS_);
    float me[3];
    #pragma unroll
    for (int i = 0; i < 3; i++) { me[i] = ws[WS_MUS + b * 3 + i] / cnt; ws[WS_MEAN + b * 3 + i] = me[i]; }
    const int dg[3] = {0, 3, 5};
    #pragma unroll
    for (int i = 0; i < 3; i++) {
      float cov = ws[WS_MOS + b * 6 + dg[i]] / cnt - me[i] * me[i];
      ws[WS_STD + b * 3 + i] = fmaxf(sqrtf(fmaxf(cov, EPS_)), SIGF_);
    }
    #pragma unroll
    for (int i = 0; i < 3; i++)
      #pragma unroll
      for (int j = 0; j < 3; j++)
        ws[WS_SIGAVG + b * 9 + i * 3 + j] =
            0.5f * (ws[WS_SGS + b * 9 + i * 3 + j] + ws[WS_SGS + b * 9 + j * 3 + i]) / cnt;
  }
}

// ---- gating + exact top-k (tie -> lower index), writes int idx + float idx output ----
__global__ __launch_bounds__(256) void k_topk(const float* __restrict__ ws_ssum,
    const float* __restrict__ gW, const float* __restrict__ pool,
    int* __restrict__ idx_o, float* __restrict__ idxf_o) {
  int b = blockIdx.x, t = threadIdx.x;
  __shared__ float sb[C_], qv[C_], sc[KMAX_];
  __shared__ float rv[256]; __shared__ int ri[256];
  sb[t] = ws_ssum[b * C_ + t];  // raw sum; l2-normalization makes the 1/cnt scale irrelevant
  __syncthreads();
  float qr = 0.f;
  for (int c = 0; c < C_; c++) qr += sb[c] * gW[(size_t)t * C_ + c];
  float n2 = blk_red(qr * qr, rv, t);
  qv[t] = qr / fmaxf(sqrtf(n2), 1e-12f);
  __syncthreads();
  for (int j = t; j < KMAX_; j += 256) {
    float d = 0.f, p2 = 0.f;
    const float* pr = pool + (size_t)j * C_;
    for (int c = 0; c < C_; c++) { float pv = pr[c]; d += qv[c] * pv; p2 += pv * pv; }
    sc[j] = d / fmaxf(sqrtf(p2), 1e-12f);
  }
  __syncthreads();
  for (int it = 0; it < KU_; it++) {
    float bv = -INFINITY; int bi = KMAX_;
    #pragma unroll
    for (int jj = 0; jj < KMAX_ / 256; jj++) {
      int j = t + jj * 256;
      float vv = sc[j];
      if (vv > bv || (vv == bv && j < bi)) { bv = vv; bi = j; }
    }
    rv[t] = bv; ri[t] = bi; __syncthreads();
    for (int s2 = 128; s2 > 0; s2 >>= 1) {
      if (t < s2) {
        float ov = rv[t + s2]; int oi = ri[t + s2];
        if (ov > rv[t] || (ov == rv[t] && oi < ri[t])) { rv[t] = ov; ri[t] = oi; }
      }
      __syncthreads();
    }
    if (t == 0) {
      idx_o[b * KU_ + it] = ri[0];
      idxf_o[b * KU_ + it] = (float)ri[0];
      sc[ri[0]] = -INFINITY;
    }
    __syncthreads();
  }
}

// ---- init slots / mu_k / Sig_k ----
__global__ __launch_bounds__(256) void k_init(const int* __restrict__ idx,
    const float* __restrict__ pool, const float* __restrict__ geop,
    const float* __restrict__ ws, float* __restrict__ slots,
    float* __restrict__ mu_k, float* __restrict__ sig_k) {
  int blk = blockIdx.x; int b = blk / KU_, k = blk % KU_; int t = threadIdx.x;
  int j = idx[b * KU_ + k];
  slots[((size_t)(b * KU_ + k)) * C_ + t] = pool[(size_t)j * C_ + t];
  if (t < 3) {
    mu_k[(b * KU_ + k) * 3 + t] = ws[WS_MEAN + b * 3 + t] + geop[j * 3 + t] * (0.5f * ws[WS_STD + b * 3 + t]);
  }
  if (t < 9) {
    float v = ws[WS_SIGAVG + b * 9 + t] * 0.1f;
    if (t == 0 || t == 4 || t == 8) v += SIGF_ * SIGF_ + JIT_;
    sig_k[((size_t)(b * KU_ + k)) * 9 + t] = v;
  }
}

// ---- generic row GEMM: out[r,i] = (ACC? out :0) + act( sum_c in[r,c]*W[i,c] + bias[i] ) ----
template<int ROWS, int OPT, bool HASB, bool ACC, bool GELU_>
__global__ __launch_bounds__(256) void k_gemm(const float* __restrict__ in,
    const float* __restrict__ W, const float* __restrict__ bias,
    float* __restrict__ out, int R, int IN, int OUT) {
  extern __shared__ float sm[];
  int t = threadIdx.x; int r0 = blockIdx.x * ROWS;
  for (int i = t; i < ROWS * IN; i += 256) {
    int rr = i / IN, c = i % IN; int r = r0 + rr;
    sm[i] = (r < R) ? in[(size_t)r * IN + c] : 0.f;
  }
  __syncthreads();
  float acc[ROWS][OPT];
  #pragma unroll
  for (int a = 0; a < ROWS; a++)
    #pragma unroll
    for (int j = 0; j < OPT; j++) acc[a][j] = 0.f;
  for (int c = 0; c < IN; c++) {
    float wv[OPT];
    #pragma unroll
    for (int j = 0; j < OPT; j++) wv[j] = W[(size_t)(t + j * 256) * IN + c];
    #pragma unroll
    for (int a = 0; a < ROWS; a++) {
      float sv = sm[a * IN + c];
      #pragma unroll
      for (int j = 0; j < OPT; j++) acc[a][j] += sv * wv[j];
    }
  }
  for (int a = 0; a < ROWS; a++) {
    int r = r0 + a; if (r >= R) break;
    #pragma unroll
    for (int j = 0; j < OPT; j++) {
      int i = t + j * 256;
      float v = acc[a][j];
      if (HASB) v += bias[i];
      if (GELU_) v = 0.5f * v * (1.0f + erff(v * 0.70710678118654752f));
      if (ACC) out[(size_t)r * OUT + i] += v;
      else out[(size_t)r * OUT + i] = v;
    }
  }
}

// ---- logits_sem: A[b,n,k] = dot(k_sem[b,n,:], q_sem[b,k,:]) / 16 ----
__global__ __launch_bounds__(256) void k_logits(const float* __restrict__ ksem,
    const float* __restrict__ qsem, float* __restrict__ A) {
  int blk = blockIdx.x; int b = blk / (N_ / 16); int nt = blk % (N_ / 16); int t = threadIdx.x;
  __shared__ float sm[16 * C_];
  int r0 = nt * 16;
  for (int i = t; i < 16 * C_; i += 256) {
    int rr = i / C_, c = i % C_;
    sm[i] = ksem[((size_t)(b * N_ + r0 + rr)) * C_ + c];
  }
  __syncthreads();
  if (t >= KU_) return;
  const float* q = qsem + ((size_t)(b * KU_ + t)) * C_;
  float acc[16];
  #pragma unroll
  for (int a = 0; a < 16; a++) acc[a] = 0.f;
  for (int c = 0; c < C_; c++) {
    float wv = q[c];
    #pragma unroll
    for (int a = 0; a < 16; a++) acc[a] += sm[a * C_ + c] * wv;
  }
  #pragma unroll
  for (int a = 0; a < 16; a++)
    A[((size_t)(b * N_ + r0 + a)) * KU_ + t] = acc[a] * 0.0625f;
}

// ---- fused geo term + softmax, in-place on A; one thread per (b,n) ----
__global__ __launch_bounds__(64) void k_geosm(const float* __restrict__ mu,
    const float* __restrict__ Sigma, const float* __restrict__ mask,
    const float* __restrict__ mu_k, const float* __restrict__ sig_k,
    const float* __restrict__ wgeo, const float* __restrict__ gsr,
    const float* __restrict__ gbias, float* __restrict__ A) {
  int blk = blockIdx.x; int b = blk / (N_ / 64); int nb = blk % (N_ / 64); int t = threadIdx.x;
  int n = nb * 64 + t;
  __shared__ float muk[KU_ * 3], sgk[KU_ * 6];
  for (int i = t; i < KU_ * 3; i += 64) muk[i] = mu_k[(size_t)b * KU_ * 3 + i];
  for (int i = t; i < KU_ * 6; i += 64) {
    int k = i / 6, c = i % 6;
    const int map[6] = {0, 1, 2, 4, 5, 8};
    sgk[i] = sig_k[((size_t)(b * KU_ + k)) * 9 + map[c]];
  }
  __syncthreads();
  float ah = 0.f, bs = 0.f;
  #pragma unroll
  for (int h = 0; h < H_; h++) {
    float x = gsr[h];
    ah += fmaxf(x, 0.f) + log1pf(expf(-fabsf(x)));  // softplus
    bs += gbias[h];
  }
  float wg = wgeo[0];
  float m = mask[b * N_ + n];
  const float* mun = mu + ((size_t)(b * N_ + n)) * 3;
  const float* sgn = Sigma + ((size_t)(b * N_ + n)) * 9;
  float u0 = mun[0], u1 = mun[1], u2 = mun[2];
  float g00 = sgn[0], g01 = sgn[1], g02 = sgn[2], g11 = sgn[4], g12 = sgn[5], g22 = sgn[8];
  float* Arow = A + ((size_t)(b * N_ + n)) * KU_;
  float mmax = -INFINITY;
  for (int k = 0; k < KU_; k++) {
    float d0 = u0 - muk[k * 3], d1 = u1 - muk[k * 3 + 1], d2 = u2 - muk[k * 3 + 2];
    float s00 = g00 + sgk[k * 6], s01 = g01 + sgk[k * 6 + 1], s02 = g02 + sgk[k * 6 + 2];
    float s11 = g11 + sgk[k * 6 + 3], s12 = g12 + sgk[k * 6 + 4], s22 = g22 + sgk[k * 6 + 5];
    float c00 = s11 * s22 - s12 * s12;
    float c01 = s02 * s12 - s01 * s22;
    float c02 = s01 * s12 - s02 * s11;
    float det = s00 * c00 + s01 * c01 + s02 * c02;
    float c11 = s00 * s22 - s02 * s02;
    float c12 = s01 * s02 - s00 * s12;
    float c22 = s00 * s11 - s01 * s01;
    float inv = 1.0f / det;
    float x0 = (c00 * d0 + c01 * d1 + c02 * d2) * inv;
    float x1 = (c01 * d0 + c11 * d1 + c12 * d2) * inv;
    float x2 = (c02 * d0 + c12 * d1 + c22 * d2) * inv;
    float maha = d0 * x0 + d1 * x1 + d2 * x2;
    float logdet = logf(fmaxf(det, 1e-30f));
    float G = -0.5f * (maha + logdet);
    float l = Arow[k] + wg * (ah * G + bs);
    if (m < 0.5f) l = -1e9f;
    Arow[k] = l;
    mmax = fmaxf(mmax, l);
  }
  float ssum = 0.f;
  for (int k = 0; k < KU_; k++) { float e = expf(Arow[k] - mmax); Arow[k] = e; ssum += e; }
  float sc = m / ssum;
  for (int k = 0; k < KU_; k++) Arow[k] *= sc;
}

// ---- occ + new mu_k ----
__global__ __launch_bounds__(256) void k_accum1(const float* __restrict__ A,
    const float* __restrict__ mu, float* __restrict__ occ, float* __restrict__ mu_k) {
  int blk = blockIdx.x; int b = blk / KU_, k = blk % KU_; int t = threadIdx.x;
  float o = 0.f, a0 = 0.f, a1 = 0.f, a2 = 0.f;
  for (int n = t; n < N_; n += 256) {
    float a = A[((size_t)(b * N_ + n)) * KU_ + k];
    const float* mr = mu + ((size_t)(b * N_ + n)) * 3;
    o += a; a0 += a * mr[0]; a1 += a * mr[1]; a2 += a * mr[2];
  }
  __shared__ float red[256];
  o = blk_red(o, red, t); a0 = blk_red(a0, red, t);
  a1 = blk_red(a1, red, t); a2 = blk_red(a2, red, t);
  if (t == 0) {
    occ[b * KU_ + k] = o;
    float oc = fmaxf(o, EPS_);
    mu_k[(b * KU_ + k) * 3 + 0] = a0 / oc;
    mu_k[(b * KU_ + k) * 3 + 1] = a1 / oc;
    mu_k[(b * KU_ + k) * 3 + 2] = a2 / oc;
  }
}

// ---- new Sig_k ----
__global__ __launch_bounds__(256) void k_accum2(const float* __restrict__ A,
    const float* __restrict__ mu, const float* __restrict__ Sigma,
    const float* __restrict__ occ, const float* __restrict__ mu_k,
    float* __restrict__ sig_k) {
  int blk = blockIdx.x; int b = blk / KU_, k = blk % KU_; int t = threadIdx.x;
  float q0 = mu_k[(b * KU_ + k) * 3 + 0];
  float q1 = mu_k[(b * KU_ + k) * 3 + 1];
  float q2 = mu_k[(b * KU_ + k) * 3 + 2];
  float s00 = 0.f, s01 = 0.f, s02 = 0.f, s11 = 0.f, s12 = 0.f, s22 = 0.f;
  for (int n = t; n < N_; n += 256) {
    float a = A[((size_t)(b * N_ + n)) * KU_ + k];
    const float* mr = mu + ((size_t)(b * N_ + n)) * 3;
    const float* sg = Sigma + ((size_t)(b * N_ + n)) * 9;
    float d0 = mr[0] - q0, d1 = mr[1] - q1, d2 = mr[2] - q2;
    s00 += a * (sg[0] + d0 * d0); s01 += a * (sg[1] + d0 * d1); s02 += a * (sg[2] + d0 * d2);
    s11 += a * (sg[4] + d1 * d1); s12 += a * (sg[5] + d1 * d2); s22 += a * (sg[8] + d2 * d2);
  }
  __shared__ float red[256];
  s00 = blk_red(s00, red, t); s01 = blk_red(s01, red, t); s02 = blk_red(s02, red, t);
  s11 = blk_red(s11, red, t); s12 = blk_red(s12, red, t); s22 = blk_red(s22, red, t);
  if (t == 0) {
    float oc = fmaxf(occ[b * KU_ + k], EPS_);
    float v00 = s00 / oc + JIT_, v11 = s11 / oc + JIT_, v22 = s22 / oc + JIT_;
    float v01 = s01 / oc, v02 = s02 / oc, v12 = s12 / oc;
    v00 = fmaxf(v00, SIGF_ * SIGF_) + JIT_;
    v11 = fmaxf(v11, SIGF_ * SIGF_) + JIT_;
    v22 = fmaxf(v22, SIGF_ * SIGF_) + JIT_;
    float* o = sig_k + ((size_t)(b * KU_ + k)) * 9;
    o[0] = v00; o[1] = v01; o[2] = v02;
    o[3] = v01; o[4] = v11; o[5] = v12;
    o[6] = v02; o[7] = v12; o[8] = v22;
  }
}

// ---- out[b,k,c] += sum_{n in chunk} A[b,n,k] * X[b,n,c]  (slot_in: X=s NX=256; AtA: X=A NX=171) ----
__global__ __launch_bounds__(256) void k_atn(const float* __restrict__ A,
    const float* __restrict__ X, float* __restrict__ out, int NX) {
  int blk = blockIdx.x;
  int nc = blk & 7; int tmp = blk >> 3; int kt = tmp % 11; int b = tmp / 11;
  int t = threadIdx.x; int k0 = kt * 16;
  __shared__ float Ach[64 * 16];
  float acc[16];
  #pragma unroll
  for (int j = 0; j < 16; j++) acc[j] = 0.f;
  for (int n0 = nc * 256; n0 < nc * 256 + 256; n0 += 64) {
    __syncthreads();
    for (int i = t; i < 64 * 16; i += 256) {
      int nn = i >> 4, kk = i & 15; int k = k0 + kk;
      Ach[i] = (k < KU_) ? A[((size_t)(b * N_ + n0 + nn)) * KU_ + k] : 0.f;
    }
    __syncthreads();
    if (t < NX) {
      for (int nn = 0; nn < 64; nn++) {
        float xv = X[((size_t)(b * N_ + n0 + nn)) * NX + t];
        #pragma unroll
        for (int j = 0; j < 16; j++) acc[j] += Ach[(nn << 4) + j] * xv;
      }
    }
  }
  if (t < NX) {
    #pragma unroll
    for (int j = 0; j < 16; j++) {
      int k = k0 + j;
      if (k < KU_) atomicAdd(&out[((size_t)(b * KU_ + k)) * NX + t], acc[j]);
    }
  }
}

__global__ __launch_bounds__(256) void k_slotdiv(const float* __restrict__ occ,
    float* __restrict__ slot_in) {
  int g = blockIdx.x * 256 + threadIdx.x;
  int r = g / C_;
  slot_in[g] /= fmaxf(occ[r], 1e-8f);
}

__global__ __launch_bounds__(256) void k_gru(const float* __restrict__ gi,
    const float* __restrict__ gh, float* __restrict__ slots) {
  int g = blockIdx.x * 256 + threadIdx.x;
  int r = g / C_, c = g % C_;
  const float* gir = gi + (size_t)r * 768; const float* ghr = gh + (size_t)r * 768;
  float rg = 1.f / (1.f + expf(-(gir[c] + ghr[c])));
  float z = 1.f / (1.f + expf(-(gir[C_ + c] + ghr[C_ + c])));
  float ng = tanhf(gir[2 * C_ + c] + rg * ghr[2 * C_ + c]);
  float h = slots[g];
  slots[g] = (1.f - z) * ng + z * h;
}

__global__ __launch_bounds__(256) void k_ln(const float* __restrict__ slots,
    const float* __restrict__ g, const float* __restrict__ bb, float* __restrict__ xm) {
  int r = blockIdx.x, t = threadIdx.x;
  float x = slots[(size_t)r * C_ + t];
  __shared__ float red[256];
  float mean = blk_red(x, red, t) * (1.0f / C_);
  float d = x - mean;
  float var = blk_red(d * d, red, t) * (1.0f / C_);
  xm[(size_t)r * C_ + t] = d / sqrtf(var + 1e-5f) * g[t] + bb[t];
}

__global__ __launch_bounds__(256) void k_hist(const int* __restrict__ idx,
    float* __restrict__ okl, float* __restrict__ oent) {
  __shared__ float hist[KMAX_];
  int t = threadIdx.x;
  for (int i = t; i < KMAX_; i += 256) hist[i] = 0.f;
  __syncthreads();
  for (int i = t; i < B_ * KU_; i += 256) atomicAdd(&hist[idx[i]], 1.0f);
  __syncthreads();
  float kl = 0.f, ent = 0.f;
  const float tot = (float)(B_ * KU_);
  for (int i = t; i < KMAX_; i += 256) {
    float pc = fmaxf(hist[i] / tot, 1e-8f);
    float lp = logf(pc);
    kl += pc * (lp + LOGKMAX_);
    ent += pc * lp;
  }
  __shared__ float red[256];
  kl = blk_red(kl, red, t); ent = blk_red(ent, red, t);
  if (t == 0) { okl[0] = kl; oent[0] = ent; }
}

__global__ __launch_bounds__(256) void k_occmse(const float* __restrict__ occ,
    float* __restrict__ out) {
  __shared__ float so[B_ * KU_];
  int t = threadIdx.x;
  for (int i = t; i < B_ * KU_; i += 256) so[i] = occ[i];
  __syncthreads();
  __shared__ float red[256];
  __shared__ float bsum[B_];
  for (int b = 0; b < B_; b++) {
    float s = 0.f;
    for (int i = t; i < KU_; i += 256) s += so[b * KU_ + i];
    s = blk_red(s, red, t);
    if (t == 0) bsum[b] = fmaxf(s, 1e-8f);
    __syncthreads();
  }
  float acc = 0.f;
  const float invK = 1.0f / (float)KU_;
  for (int i = t; i < B_ * KU_; i += 256) {
    int b = i / KU_;
    float v = so[i] / bsum[b] - invK;
    acc += v * v;
  }
  acc = blk_red(acc, red, t);
  if (t == 0) out[0] = acc / (float)(B_ * KU_);
}

__global__ __launch_bounds__(256) void k_col(const float* __restrict__ AtA,
    const float* __restrict__ okl, const float* __restrict__ oent,
    const float* __restrict__ oocc, float* __restrict__ ocol, float* __restrict__ otot) {
  __shared__ float nrm[B_ * KU_];
  int t = threadIdx.x;
  for (int i = t; i < B_ * KU_; i += 256) {
    int b = i / KU_, k = i % KU_;
    nrm[i] = fmaxf(sqrtf(AtA[((size_t)(b * KU_ + k)) * KU_ + k]), 1e-8f);
  }
  __syncthreads();
  float acc = 0.f;
  const int TOT = B_ * KU_ * KU_;
  for (int i = t; i < TOT; i += 256) {
    int b = i / (KU_ * KU_); int rem = i % (KU_ * KU_); int k = rem / KU_, l = rem % KU_;
    if (k == l) continue;
    float gm = AtA[i] / (nrm[b * KU_ + k] * nrm[b * KU_ + l]);
    acc += gm * gm;
  }
  __shared__ float red[256];
  acc = blk_red(acc, red, t);
  if (t == 0) {
    float col = acc / (float)TOT;
    ocol[0] = col;
    otot[0] = 0.05f * okl[0] + 0.0f * oent[0] + 0.5f * oocc[0] + 0.1f * col;
  }
}

extern "C" void kernel_launch(void* const* d_in, const int* in_sizes, int n_in,
                              void* d_out_v, int out_size, void* d_ws, size_t ws_size,
                              hipStream_t stream) {
  const float* s     = (const float*)d_in[0];
  const float* mu    = (const float*)d_in[1];
  const float* Sigma = (const float*)d_in[2];
  const float* mask  = (const float*)d_in[3];
  const float* pool  = (const float*)d_in[4];
  const float* geop  = (const float*)d_in[5];
  const float* gW    = (const float*)d_in[6];
  const float* qW    = (const float*)d_in[7];
  const float* kW    = (const float*)d_in[8];
  const float* wih   = (const float*)d_in[9];
  const float* whh   = (const float*)d_in[10];
  const float* bih   = (const float*)d_in[11];
  const float* bhh   = (const float*)d_in[12];
  const float* lng   = (const float*)d_in[13];
  const float* lnb   = (const float*)d_in[14];
  const float* w1    = (const float*)d_in[15];
  const float* b1    = (const float*)d_in[16];
  const float* w2    = (const float*)d_in[17];
  const float* b2    = (const float*)d_in[18];
  const float* wgeo  = (const float*)d_in[19];
  const float* gsr   = (const float*)d_in[20];
  const float* gbias = (const float*)d_in[21];

  float* out = (float*)d_out_v;
  float* A     = out + O_A;
  float* slots = out + O_SLOTS;
  float* muk   = out + O_MUK;
  float* sigk  = out + O_SIGK;
  float* idxf  = out + O_IDX;
  float* okl   = out + O_KL;
  float* oent  = out + O_ENT;
  float* oocc  = out + O_OCC;
  float* ocol  = out + O_COL;
  float* otot  = out + O_TOT;

  float* ws = (float*)d_ws;
  int*   idxi   = (int*)(ws + WS_IDXI);
  float* ksem   = ws + WS_KSEM;
  float* qsem   = ws + WS_QSEM;
  float* occ    = ws + WS_OCC;
  float* slotin = ws + WS_SLOTIN;
  float* gi     = ws + WS_GI;
  float* gh     = ws + WS_GH;
  float* xm     = ws + WS_XM;
  float* hid    = ws + WS_HID;
  float* ata    = ws + WS_ATA;

  // stage 0: stats + gating + top-k + init
  hipMemsetAsync(ws, 0, WS_STATS_BYTES, stream);
  k_stats<<<B_ * 8, 256, 0, stream>>>(s, mu, Sigma, mask, ws);
  k_fin<<<1, 64, 0, stream>>>(ws);
  k_topk<<<B_, 256, 0, stream>>>(ws + WS_SSUM, gW, pool, idxi, idxf);
  k_init<<<B_ * KU_, 256, 0, stream>>>(idxi, pool, geop, ws, slots, muk, sigk);

  // k_sem = s @ proj_k_W.T
  k_gemm<8, 1, false, false, false><<<(B_ * N_) / 8, 256, 8 * C_ * 4, stream>>>(
      s, kW, nullptr, ksem, B_ * N_, C_, C_);

  const int RBK = (B_ * KU_ + 7) / 8;  // 86
  for (int it = 0; it < ITERS_; ++it) {
    k_gemm<8, 1, false, false, false><<<RBK, 256, 8 * C_ * 4, stream>>>(
        slots, qW, nullptr, qsem, B_ * KU_, C_, C_);
    k_logits<<<B_ * (N_ / 16), 256, 0, stream>>>(ksem, qsem, A);
    k_geosm<<<B_ * (N_ / 64), 64, 0, stream>>>(mu, Sigma, mask, muk, sigk, wgeo, gsr, gbias, A);
    k_accum1<<<B_ * KU_, 256, 0, stream>>>(A, mu, occ, muk);
    k_accum2<<<B_ * KU_, 256, 0, stream>>>(A, mu, Sigma, occ, muk, sigk);
    hipMemsetAsync(slotin, 0, (size_t)B_ * KU_ * C_ * 4, stream);
    k_atn<<<B_ * 11 * 8, 256, 0, stream>>>(A, s, slotin, C_);
    k_slotdiv<<<B_ * KU_, 256, 0, stream>>>(occ, slotin);
    k_gemm<8, 3, true, false, false><<<RBK, 256, 8 * C_ * 4, stream>>>(
        slotin, wih, bih, gi, B_ * KU_, C_, 3 * C_);
    k_gemm<8, 3, true, false, false><<<RBK, 256, 8 * C_ * 4, stream>>>(
        slots, whh, bhh, gh, B_ * KU_, C_, 3 * C_);
    k_gru<<<B_ * KU_, 256, 0, stream>>>(gi, gh, slots);
    k_ln<<<B_ * KU_, 256, 0, stream>>>(slots, lng, lnb, xm);
    k_gemm<8, 4, true, false, true><<<RBK, 256, 8 * C_ * 4, stream>>>(
        xm, w1, b1, hid, B_ * KU_, C_, 4 * C_);
    k_gemm<8, 1, true, true, false><<<RBK, 256, 8 * 1024 * 4, stream>>>(
        hid, w2, b2, slots, B_ * KU_, 4 * C_, C_);
  }

  // losses
  hipMemsetAsync(ata, 0, (size_t)B_ * KU_ * KU_ * 4, stream);
  k_atn<<<B_ * 11 * 8, 256, 0, stream>>>(A, A, ata, KU_);
  k_hist<<<1, 256, 0, stream>>>(idxi, okl, oent);
  k_occmse<<<1, 256, 0, stream>>>(occ, oocc);
  k_col<<<1, 256, 0, stream>>>(ata, okl, oent, oocc, ocol, otot);
}

// Round 2
// 1459.044 us; speedup vs baseline: 1.2404x; 1.2404x over previous
//
#include <hip/hip_runtime.h>
#include <math.h>

#define B_ 4
#define N_ 2048
#define C_ 256
#define KMAX_ 1024
#define KU_ 171
#define ITERS_ 3
#define H_ 4
#define EPS_ 1e-8f
#define SIGF_ 0.03f
#define JIT_ 1e-6f
#define LOGKMAX_ 6.93147180559945f

// ---------------- workspace layout (float offsets) ----------------
#define WS_CNT 0          // 4
#define WS_MUS 4          // 12
#define WS_MOS 16         // 24 (6 per batch: 00,01,02,11,12,22)
#define WS_SGS 40         // 36
#define WS_SSUM 128       // 1024
#define WS_STATS_BYTES (1152*4)
#define WS_MEAN 1152      // 12
#define WS_STD 1164       // 12
#define WS_SIGAVG 1176    // 36
#define WS_IDXI 1216      // 684 ints (pad to 1920)
#define WS_KSEM 1920                  // B*N*C = 2097152
#define WS_QSEM (WS_KSEM+2097152)     // 175104
#define WS_OCC  (WS_QSEM+175104)      // 684 (pad 704)
#define WS_SLOTIN (WS_OCC+704)        // 175104
#define WS_GI (WS_SLOTIN+175104)      // 525312
#define WS_GH (WS_GI+525312)          // 525312
#define WS_XM (WS_GH+525312)          // 175104
#define WS_HID (WS_XM+175104)         // 700416
#define WS_ATA (WS_HID+700416)        // 116964

// ---------------- output layout (float offsets) ----------------
#define O_A 0
#define O_SLOTS 1400832
#define O_MUK   1575936
#define O_SIGK  1577988
#define O_IDX   1584144
#define O_KL    1584828
#define O_ENT   1584829
#define O_OCC   1584830
#define O_COL   1584831
#define O_TOT   1584832

__device__ __forceinline__ float blk_red(float v, float* red, int t) {
  red[t] = v; __syncthreads();
  #pragma unroll
  for (int s = 128; s > 0; s >>= 1) {
    if (t < s) red[t] += red[t + s];
    __syncthreads();
  }
  float r = red[0]; __syncthreads();
  return r;
}

// ---- partial batch stats: cnt, sum(m*mu), sum(m*mu mu^T), sum(m*Sigma), sum(m*s) ----
__global__ __launch_bounds__(256) void k_stats(const float* __restrict__ s,
    const float* __restrict__ mu, const float* __restrict__ Sigma,
    const float* __restrict__ mask, float* __restrict__ ws) {
  int blk = blockIdx.x; int b = blk / 8; int nc = blk % 8; int t = threadIdx.x;
  int n = nc * 256 + t;
  float m = mask[b * N_ + n];
  const float* mun = mu + ((size_t)(b * N_ + n)) * 3;
  float m0 = mun[0], m1v = mun[1], m2 = mun[2];
  const float* sgn = Sigma + ((size_t)(b * N_ + n)) * 9;
  float sg[9];
  #pragma unroll
  for (int j = 0; j < 9; j++) sg[j] = sgn[j];
  __shared__ float red[256];
  float v;
  v = blk_red(m, red, t);           if (t == 0) atomicAdd(ws + WS_CNT + b, v);
  v = blk_red(m * m0, red, t);      if (t == 0) atomicAdd(ws + WS_MUS + b * 3 + 0, v);
  v = blk_red(m * m1v, red, t);     if (t == 0) atomicAdd(ws + WS_MUS + b * 3 + 1, v);
  v = blk_red(m * m2, red, t);      if (t == 0) atomicAdd(ws + WS_MUS + b * 3 + 2, v);
  v = blk_red(m * m0 * m0, red, t); if (t == 0) atomicAdd(ws + WS_MOS + b * 6 + 0, v);
  v = blk_red(m * m0 * m1v, red, t);if (t == 0) atomicAdd(ws + WS_MOS + b * 6 + 1, v);
  v = blk_red(m * m0 * m2, red, t); if (t == 0) atomicAdd(ws + WS_MOS + b * 6 + 2, v);
  v = blk_red(m * m1v * m1v, red, t);if (t == 0) atomicAdd(ws + WS_MOS + b * 6 + 3, v);
  v = blk_red(m * m1v * m2, red, t);if (t == 0) atomicAdd(ws + WS_MOS + b * 6 + 4, v);
  v = blk_red(m * m2 * m2, red, t); if (t == 0) atomicAdd(ws + WS_MOS + b * 6 + 5, v);
  #pragma unroll
  for (int j = 0; j < 9; j++) {
    v = blk_red(m * sg[j], red, t);
    if (t == 0) atomicAdd(ws + WS_SGS + b * 9 + j, v);
  }
  // s-column sums: thread t owns column c=t over this block's 256 rows
  const float* sb = s + ((size_t)b * N_ + nc * 256) * C_;
  const float* mk = mask + b * N_ + nc * 256;
  float sa = 0.f;
  for (int nn = 0; nn < 256; nn++) sa += mk[nn] * sb[(size_t)nn * C_ + t];
  atomicAdd(ws + WS_SSUM + b * C_ + t, sa);
}

// ---- finalize mean/std/sigavg ----
__global__ __launch_bounds__(64) void k_fin(float* __restrict__ ws) {
  int t = threadIdx.x;
  if (t < B_) {
    int b = t;
    float cnt = fmaxf(ws[WS_CNT + b], EPS_);
    float me[3];
    #pragma unroll
    for (int i = 0; i < 3; i++) { me[i] = ws[WS_MUS + b * 3 + i] / cnt; ws[WS_MEAN + b * 3 + i] = me[i]; }
    const int dg[3] = {0, 3, 5};
    #pragma unroll
    for (int i = 0; i < 3; i++) {
      float cov = ws[WS_MOS + b * 6 + dg[i]] / cnt - me[i] * me[i];
      ws[WS_STD + b * 3 + i] = fmaxf(sqrtf(fmaxf(cov, EPS_)), SIGF_);
    }
    #pragma unroll
    for (int i = 0; i < 3; i++)
      #pragma unroll
      for (int j = 0; j < 3; j++)
        ws[WS_SIGAVG + b * 9 + i * 3 + j] =
            0.5f * (ws[WS_SGS + b * 9 + i * 3 + j] + ws[WS_SGS + b * 9 + j * 3 + i]) / cnt;
  }
}

// ---- gating + top-k via full bitonic sort of (score, idx); order == jax.lax.top_k ----
__global__ __launch_bounds__(256) void k_topk(const float* __restrict__ ws_ssum,
    const float* __restrict__ gW, const float* __restrict__ pool,
    int* __restrict__ idx_o, float* __restrict__ idxf_o) {
  int b = blockIdx.x, t = threadIdx.x;
  __shared__ float sb[C_], qv[C_];
  __shared__ float val[KMAX_]; __shared__ int id[KMAX_];
  __shared__ float rv[256];
  sb[t] = ws_ssum[b * C_ + t];  // raw sum; l2-normalization makes the 1/cnt scale irrelevant
  __syncthreads();
  float qr = 0.f;
  for (int c = 0; c < C_; c++) qr += sb[c] * gW[(size_t)t * C_ + c];
  float n2 = blk_red(qr * qr, rv, t);
  qv[t] = qr / fmaxf(sqrtf(n2), 1e-12f);
  __syncthreads();
  for (int j = t; j < KMAX_; j += 256) {
    float d = 0.f, p2 = 0.f;
    const float* pr = pool + (size_t)j * C_;
    for (int c = 0; c < C_; c++) { float pv = pr[c]; d += qv[c] * pv; p2 += pv * pv; }
    val[j] = d / fmaxf(sqrtf(p2), 1e-12f);
    id[j] = j;
  }
  __syncthreads();
  // bitonic sort, best-first: before(a,b) == a.v > b.v || (a.v==b.v && a.i < b.i)
  for (int kk = 2; kk <= KMAX_; kk <<= 1) {
    for (int j = kk >> 1; j > 0; j >>= 1) {
      for (int i = t; i < KMAX_; i += 256) {
        int ix = i ^ j;
        if (ix > i) {
          float va = val[i], vb = val[ix]; int ia = id[i], ib = id[ix];
          bool bBeforeA = (vb > va) || (vb == va && ib < ia);
          bool up = ((i & kk) == 0);
          if (up == bBeforeA) {
            val[i] = vb; val[ix] = va; id[i] = ib; id[ix] = ia;
          }
        }
      }
      __syncthreads();
    }
  }
  if (t < KU_) {
    idx_o[b * KU_ + t] = id[t];
    idxf_o[b * KU_ + t] = (float)id[t];
  }
}

// ---- init slots / mu_k / Sig_k ----
__global__ __launch_bounds__(256) void k_init(const int* __restrict__ idx,
    const float* __restrict__ pool, const float* __restrict__ geop,
    const float* __restrict__ ws, float* __restrict__ slots,
    float* __restrict__ mu_k, float* __restrict__ sig_k) {
  int blk = blockIdx.x; int b = blk / KU_, k = blk % KU_; int t = threadIdx.x;
  int j = idx[b * KU_ + k];
  slots[((size_t)(b * KU_ + k)) * C_ + t] = pool[(size_t)j * C_ + t];
  if (t < 3) {
    mu_k[(b * KU_ + k) * 3 + t] = ws[WS_MEAN + b * 3 + t] + geop[j * 3 + t] * (0.5f * ws[WS_STD + b * 3 + t]);
  }
  if (t < 9) {
    float v = ws[WS_SIGAVG + b * 9 + t] * 0.1f;
    if (t == 0 || t == 4 || t == 8) v += SIGF_ * SIGF_ + JIT_;
    sig_k[((size_t)(b * KU_ + k)) * 9 + t] = v;
  }
}

// ---- generic row GEMM: out[r,i] = (ACC? out :0) + act( sum_c in[r,c]*W[i,c] + bias[i] ) ----
template<int ROWS, int OPT, bool HASB, bool ACC, bool GELU_>
__global__ __launch_bounds__(256) void k_gemm(const float* __restrict__ in,
    const float* __restrict__ W, const float* __restrict__ bias,
    float* __restrict__ out, int R, int IN, int OUT) {
  extern __shared__ float sm[];
  int t = threadIdx.x; int r0 = blockIdx.x * ROWS;
  for (int i = t; i < ROWS * IN; i += 256) {
    int rr = i / IN, c = i % IN; int r = r0 + rr;
    sm[i] = (r < R) ? in[(size_t)r * IN + c] : 0.f;
  }
  __syncthreads();
  float acc[ROWS][OPT];
  #pragma unroll
  for (int a = 0; a < ROWS; a++)
    #pragma unroll
    for (int j = 0; j < OPT; j++) acc[a][j] = 0.f;
  for (int c = 0; c < IN; c++) {
    float wv[OPT];
    #pragma unroll
    for (int j = 0; j < OPT; j++) wv[j] = W[(size_t)(t + j * 256) * IN + c];
    #pragma unroll
    for (int a = 0; a < ROWS; a++) {
      float sv = sm[a * IN + c];
      #pragma unroll
      for (int j = 0; j < OPT; j++) acc[a][j] += sv * wv[j];
    }
  }
  for (int a = 0; a < ROWS; a++) {
    int r = r0 + a; if (r >= R) break;
    #pragma unroll
    for (int j = 0; j < OPT; j++) {
      int i = t + j * 256;
      float v = acc[a][j];
      if (HASB) v += bias[i];
      if (GELU_) v = 0.5f * v * (1.0f + erff(v * 0.70710678118654752f));
      if (ACC) out[(size_t)r * OUT + i] += v;
      else out[(size_t)r * OUT + i] = v;
    }
  }
}

// ---- logits_sem: A[b,n,k] = dot(k_sem[b,n,:], q_sem[b,k,:]) / 16 ----
__global__ __launch_bounds__(256) void k_logits(const float* __restrict__ ksem,
    const float* __restrict__ qsem, float* __restrict__ A) {
  int blk = blockIdx.x; int b = blk / (N_ / 16); int nt = blk % (N_ / 16); int t = threadIdx.x;
  __shared__ float sm[16 * C_];
  int r0 = nt * 16;
  for (int i = t; i < 16 * C_; i += 256) {
    int rr = i / C_, c = i % C_;
    sm[i] = ksem[((size_t)(b * N_ + r0 + rr)) * C_ + c];
  }
  __syncthreads();
  if (t >= KU_) return;
  const float* q = qsem + ((size_t)(b * KU_ + t)) * C_;
  float acc[16];
  #pragma unroll
  for (int a = 0; a < 16; a++) acc[a] = 0.f;
  for (int c = 0; c < C_; c++) {
    float wv = q[c];
    #pragma unroll
    for (int a = 0; a < 16; a++) acc[a] += sm[a * C_ + c] * wv;
  }
  #pragma unroll
  for (int a = 0; a < 16; a++)
    A[((size_t)(b * N_ + r0 + a)) * KU_ + t] = acc[a] * 0.0625f;
}

// ---- fused geo term + softmax, in-place on A; 8 threads per row, regs for softmax ----
#define GS_SUB 8
#define GS_CHUNK 22  // ceil(171/8); 8*22=176 >= 171
__global__ __launch_bounds__(256) void k_geosm(const float* __restrict__ mu,
    const float* __restrict__ Sigma, const float* __restrict__ mask,
    const float* __restrict__ mu_k, const float* __restrict__ sig_k,
    const float* __restrict__ wgeo, const float* __restrict__ gsr,
    const float* __restrict__ gbias, float* __restrict__ A) {
  int blk = blockIdx.x;                 // B_*(N_/32) = 256 blocks
  int b = blk / (N_ / 32); int nb = blk % (N_ / 32); int t = threadIdx.x;
  int rloc = t >> 3;                    // 0..31 row within block
  int sub = t & 7;                      // 0..7 k-chunk
  int n = nb * 32 + rloc;
  __shared__ float muk[KU_ * 3], sgk[KU_ * 6];
  for (int i = t; i < KU_ * 3; i += 256) muk[i] = mu_k[(size_t)b * KU_ * 3 + i];
  for (int i = t; i < KU_ * 6; i += 256) {
    int k = i / 6, c = i % 6;
    const int map[6] = {0, 1, 2, 4, 5, 8};
    sgk[i] = sig_k[((size_t)(b * KU_ + k)) * 9 + map[c]];
  }
  __syncthreads();
  float ah = 0.f, bs = 0.f;
  #pragma unroll
  for (int h = 0; h < H_; h++) {
    float x = gsr[h];
    ah += fmaxf(x, 0.f) + log1pf(expf(-fabsf(x)));  // softplus
    bs += gbias[h];
  }
  float wg = wgeo[0];
  float m = mask[b * N_ + n];
  const float* mun = mu + ((size_t)(b * N_ + n)) * 3;
  const float* sgn = Sigma + ((size_t)(b * N_ + n)) * 9;
  float u0 = mun[0], u1 = mun[1], u2 = mun[2];
  float g00 = sgn[0], g01 = sgn[1], g02 = sgn[2], g11 = sgn[4], g12 = sgn[5], g22 = sgn[8];
  float* Arow = A + ((size_t)(b * N_ + n)) * KU_;
  const int k0 = sub * GS_CHUNK;
  float lv[GS_CHUNK];
  float mmax = -INFINITY;
  #pragma unroll
  for (int kk = 0; kk < GS_CHUNK; kk++) {
    int k = k0 + kk;
    float l = -INFINITY;
    if (k < KU_) {
      float d0 = u0 - muk[k * 3], d1 = u1 - muk[k * 3 + 1], d2 = u2 - muk[k * 3 + 2];
      float s00 = g00 + sgk[k * 6], s01 = g01 + sgk[k * 6 + 1], s02 = g02 + sgk[k * 6 + 2];
      float s11 = g11 + sgk[k * 6 + 3], s12 = g12 + sgk[k * 6 + 4], s22 = g22 + sgk[k * 6 + 5];
      float c00 = s11 * s22 - s12 * s12;
      float c01 = s02 * s12 - s01 * s22;
      float c02 = s01 * s12 - s02 * s11;
      float det = s00 * c00 + s01 * c01 + s02 * c02;
      float c11 = s00 * s22 - s02 * s02;
      float c12 = s01 * s02 - s00 * s12;
      float c22 = s00 * s11 - s01 * s01;
      float inv = 1.0f / det;
      float x0 = (c00 * d0 + c01 * d1 + c02 * d2) * inv;
      float x1 = (c01 * d0 + c11 * d1 + c12 * d2) * inv;
      float x2 = (c02 * d0 + c12 * d1 + c22 * d2) * inv;
      float maha = d0 * x0 + d1 * x1 + d2 * x2;
      float logdet = logf(fmaxf(det, 1e-30f));
      float G = -0.5f * (maha + logdet);
      l = Arow[k] + wg * (ah * G + bs);
      if (m < 0.5f) l = -1e9f;
    }
    lv[kk] = l;
    mmax = fmaxf(mmax, l);
  }
  // 8-lane group reductions (lanes sub=0..7 of the same row share lane>>3)
  mmax = fmaxf(mmax, __shfl_xor(mmax, 1));
  mmax = fmaxf(mmax, __shfl_xor(mmax, 2));
  mmax = fmaxf(mmax, __shfl_xor(mmax, 4));
  float ssum = 0.f;
  #pragma unroll
  for (int kk = 0; kk < GS_CHUNK; kk++) {
    float e = expf(lv[kk] - mmax);
    lv[kk] = e;
    ssum += e;
  }
  ssum += __shfl_xor(ssum, 1);
  ssum += __shfl_xor(ssum, 2);
  ssum += __shfl_xor(ssum, 4);
  float sc = m / ssum;
  #pragma unroll
  for (int kk = 0; kk < GS_CHUNK; kk++) {
    int k = k0 + kk;
    if (k < KU_) Arow[k] = lv[kk] * sc;
  }
}

// ---- occ + new mu_k ----
__global__ __launch_bounds__(256) void k_accum1(const float* __restrict__ A,
    const float* __restrict__ mu, float* __restrict__ occ, float* __restrict__ mu_k) {
  int blk = blockIdx.x; int b = blk / KU_, k = blk % KU_; int t = threadIdx.x;
  float o = 0.f, a0 = 0.f, a1 = 0.f, a2 = 0.f;
  for (int n = t; n < N_; n += 256) {
    float a = A[((size_t)(b * N_ + n)) * KU_ + k];
    const float* mr = mu + ((size_t)(b * N_ + n)) * 3;
    o += a; a0 += a * mr[0]; a1 += a * mr[1]; a2 += a * mr[2];
  }
  __shared__ float red[256];
  o = blk_red(o, red, t); a0 = blk_red(a0, red, t);
  a1 = blk_red(a1, red, t); a2 = blk_red(a2, red, t);
  if (t == 0) {
    occ[b * KU_ + k] = o;
    float oc = fmaxf(o, EPS_);
    mu_k[(b * KU_ + k) * 3 + 0] = a0 / oc;
    mu_k[(b * KU_ + k) * 3 + 1] = a1 / oc;
    mu_k[(b * KU_ + k) * 3 + 2] = a2 / oc;
  }
}

// ---- new Sig_k ----
__global__ __launch_bounds__(256) void k_accum2(const float* __restrict__ A,
    const float* __restrict__ mu, const float* __restrict__ Sigma,
    const float* __restrict__ occ, const float* __restrict__ mu_k,
    float* __restrict__ sig_k) {
  int blk = blockIdx.x; int b = blk / KU_, k = blk % KU_; int t = threadIdx.x;
  float q0 = mu_k[(b * KU_ + k) * 3 + 0];
  float q1 = mu_k[(b * KU_ + k) * 3 + 1];
  float q2 = mu_k[(b * KU_ + k) * 3 + 2];
  float s00 = 0.f, s01 = 0.f, s02 = 0.f, s11 = 0.f, s12 = 0.f, s22 = 0.f;
  for (int n = t; n < N_; n += 256) {
    float a = A[((size_t)(b * N_ + n)) * KU_ + k];
    const float* mr = mu + ((size_t)(b * N_ + n)) * 3;
    const float* sg = Sigma + ((size_t)(b * N_ + n)) * 9;
    float d0 = mr[0] - q0, d1 = mr[1] - q1, d2 = mr[2] - q2;
    s00 += a * (sg[0] + d0 * d0); s01 += a * (sg[1] + d0 * d1); s02 += a * (sg[2] + d0 * d2);
    s11 += a * (sg[4] + d1 * d1); s12 += a * (sg[5] + d1 * d2); s22 += a * (sg[8] + d2 * d2);
  }
  __shared__ float red[256];
  s00 = blk_red(s00, red, t); s01 = blk_red(s01, red, t); s02 = blk_red(s02, red, t);
  s11 = blk_red(s11, red, t); s12 = blk_red(s12, red, t); s22 = blk_red(s22, red, t);
  if (t == 0) {
    float oc = fmaxf(occ[b * KU_ + k], EPS_);
    float v00 = s00 / oc + JIT_, v11 = s11 / oc + JIT_, v22 = s22 / oc + JIT_;
    float v01 = s01 / oc, v02 = s02 / oc, v12 = s12 / oc;
    v00 = fmaxf(v00, SIGF_ * SIGF_) + JIT_;
    v11 = fmaxf(v11, SIGF_ * SIGF_) + JIT_;
    v22 = fmaxf(v22, SIGF_ * SIGF_) + JIT_;
    float* o = sig_k + ((size_t)(b * KU_ + k)) * 9;
    o[0] = v00; o[1] = v01; o[2] = v02;
    o[3] = v01; o[4] = v11; o[5] = v12;
    o[6] = v02; o[7] = v12; o[8] = v22;
  }
}

// ---- out[b,k,c] += sum_{n in chunk} A[b,n,k] * X[b,n,c]  (slot_in: X=s NX=256; AtA: X=A NX=171) ----
__global__ __launch_bounds__(256) void k_atn(const float* __restrict__ A,
    const float* __restrict__ X, float* __restrict__ out, int NX) {
  int blk = blockIdx.x;
  int nc = blk & 7; int tmp = blk >> 3; int kt = tmp % 11; int b = tmp / 11;
  int t = threadIdx.x; int k0 = kt * 16;
  __shared__ float Ach[64 * 16];
  float acc[16];
  #pragma unroll
  for (int j = 0; j < 16; j++) acc[j] = 0.f;
  for (int n0 = nc * 256; n0 < nc * 256 + 256; n0 += 64) {
    __syncthreads();
    for (int i = t; i < 64 * 16; i += 256) {
      int nn = i >> 4, kk = i & 15; int k = k0 + kk;
      Ach[i] = (k < KU_) ? A[((size_t)(b * N_ + n0 + nn)) * KU_ + k] : 0.f;
    }
    __syncthreads();
    if (t < NX) {
      for (int nn = 0; nn < 64; nn++) {
        float xv = X[((size_t)(b * N_ + n0 + nn)) * NX + t];
        #pragma unroll
        for (int j = 0; j < 16; j++) acc[j] += Ach[(nn << 4) + j] * xv;
      }
    }
  }
  if (t < NX) {
    #pragma unroll
    for (int j = 0; j < 16; j++) {
      int k = k0 + j;
      if (k < KU_) atomicAdd(&out[((size_t)(b * KU_ + k)) * NX + t], acc[j]);
    }
  }
}

__global__ __launch_bounds__(256) void k_slotdiv(const float* __restrict__ occ,
    float* __restrict__ slot_in) {
  int g = blockIdx.x * 256 + threadIdx.x;
  int r = g / C_;
  slot_in[g] /= fmaxf(occ[r], 1e-8f);
}

__global__ __launch_bounds__(256) void k_gru(const float* __restrict__ gi,
    const float* __restrict__ gh, float* __restrict__ slots) {
  int g = blockIdx.x * 256 + threadIdx.x;
  int r = g / C_, c = g % C_;
  const float* gir = gi + (size_t)r * 768; const float* ghr = gh + (size_t)r * 768;
  float rg = 1.f / (1.f + expf(-(gir[c] + ghr[c])));
  float z = 1.f / (1.f + expf(-(gir[C_ + c] + ghr[C_ + c])));
  float ng = tanhf(gir[2 * C_ + c] + rg * ghr[2 * C_ + c]);
  float h = slots[g];
  slots[g] = (1.f - z) * ng + z * h;
}

__global__ __launch_bounds__(256) void k_ln(const float* __restrict__ slots,
    const float* __restrict__ g, const float* __restrict__ bb, float* __restrict__ xm) {
  int r = blockIdx.x, t = threadIdx.x;
  float x = slots[(size_t)r * C_ + t];
  __shared__ float red[256];
  float mean = blk_red(x, red, t) * (1.0f / C_);
  float d = x - mean;
  float var = blk_red(d * d, red, t) * (1.0f / C_);
  xm[(size_t)r * C_ + t] = d / sqrtf(var + 1e-5f) * g[t] + bb[t];
}

__global__ __launch_bounds__(256) void k_hist(const int* __restrict__ idx,
    float* __restrict__ okl, float* __restrict__ oent) {
  __shared__ float hist[KMAX_];
  int t = threadIdx.x;
  for (int i = t; i < KMAX_; i += 256) hist[i] = 0.f;
  __syncthreads();
  for (int i = t; i < B_ * KU_; i += 256) atomicAdd(&hist[idx[i]], 1.0f);
  __syncthreads();
  float kl = 0.f, ent = 0.f;
  const float tot = (float)(B_ * KU_);
  for (int i = t; i < KMAX_; i += 256) {
    float pc = fmaxf(hist[i] / tot, 1e-8f);
    float lp = logf(pc);
    kl += pc * (lp + LOGKMAX_);
    ent += pc * lp;
  }
  __shared__ float red[256];
  kl = blk_red(kl, red, t); ent = blk_red(ent, red, t);
  if (t == 0) { okl[0] = kl; oent[0] = ent; }
}

__global__ __launch_bounds__(256) void k_occmse(const float* __restrict__ occ,
    float* __restrict__ out) {
  __shared__ float so[B_ * KU_];
  int t = threadIdx.x;
  for (int i = t; i < B_ * KU_; i += 256) so[i] = occ[i];
  __syncthreads();
  __shared__ float red[256];
  __shared__ float bsum[B_];
  for (int b = 0; b < B_; b++) {
    float s = 0.f;
    for (int i = t; i < KU_; i += 256) s += so[b * KU_ + i];
    s = blk_red(s, red, t);
    if (t == 0) bsum[b] = fmaxf(s, 1e-8f);
    __syncthreads();
  }
  float acc = 0.f;
  const float invK = 1.0f / (float)KU_;
  for (int i = t; i < B_ * KU_; i += 256) {
    int b = i / KU_;
    float v = so[i] / bsum[b] - invK;
    acc += v * v;
  }
  acc = blk_red(acc, red, t);
  if (t == 0) out[0] = acc / (float)(B_ * KU_);
}

__global__ __launch_bounds__(256) void k_col(const float* __restrict__ AtA,
    const float* __restrict__ okl, const float* __restrict__ oent,
    const float* __restrict__ oocc, float* __restrict__ ocol, float* __restrict__ otot) {
  __shared__ float nrm[B_ * KU_];
  int t = threadIdx.x;
  for (int i = t; i < B_ * KU_; i += 256) {
    int b = i / KU_, k = i % KU_;
    nrm[i] = fmaxf(sqrtf(AtA[((size_t)(b * KU_ + k)) * KU_ + k]), 1e-8f);
  }
  __syncthreads();
  float acc = 0.f;
  const int TOT = B_ * KU_ * KU_;
  for (int i = t; i < TOT; i += 256) {
    int b = i / (KU_ * KU_); int rem = i % (KU_ * KU_); int k = rem / KU_, l = rem % KU_;
    if (k == l) continue;
    float gm = AtA[i] / (nrm[b * KU_ + k] * nrm[b * KU_ + l]);
    acc += gm * gm;
  }
  __shared__ float red[256];
  acc = blk_red(acc, red, t);
  if (t == 0) {
    float col = acc / (float)TOT;
    ocol[0] = col;
    otot[0] = 0.05f * okl[0] + 0.0f * oent[0] + 0.5f * oocc[0] + 0.1f * col;
  }
}

extern "C" void kernel_launch(void* const* d_in, const int* in_sizes, int n_in,
                              void* d_out_v, int out_size, void* d_ws, size_t ws_size,
                              hipStream_t stream) {
  const float* s     = (const float*)d_in[0];
  const float* mu    = (const float*)d_in[1];
  const float* Sigma = (const float*)d_in[2];
  const float* mask  = (const float*)d_in[3];
  const float* pool  = (const float*)d_in[4];
  const float* geop  = (const float*)d_in[5];
  const float* gW    = (const float*)d_in[6];
  const float* qW    = (const float*)d_in[7];
  const float* kW    = (const float*)d_in[8];
  const float* wih   = (const float*)d_in[9];
  const float* whh   = (const float*)d_in[10];
  const float* bih   = (const float*)d_in[11];
  const float* bhh   = (const float*)d_in[12];
  const float* lng   = (const float*)d_in[13];
  const float* lnb   = (const float*)d_in[14];
  const float* w1    = (const float*)d_in[15];
  const float* b1    = (const float*)d_in[16];
  const float* w2    = (const float*)d_in[17];
  const float* b2    = (const float*)d_in[18];
  const float* wgeo  = (const float*)d_in[19];
  const float* gsr   = (const float*)d_in[20];
  const float* gbias = (const float*)d_in[21];

  float* out = (float*)d_out_v;
  float* A     = out + O_A;
  float* slots = out + O_SLOTS;
  float* muk   = out + O_MUK;
  float* sigk  = out + O_SIGK;
  float* idxf  = out + O_IDX;
  float* okl   = out + O_KL;
  float* oent  = out + O_ENT;
  float* oocc  = out + O_OCC;
  float* ocol  = out + O_COL;
  float* otot  = out + O_TOT;

  float* ws = (float*)d_ws;
  int*   idxi   = (int*)(ws + WS_IDXI);
  float* ksem   = ws + WS_KSEM;
  float* qsem   = ws + WS_QSEM;
  float* occ    = ws + WS_OCC;
  float* slotin = ws + WS_SLOTIN;
  float* gi     = ws + WS_GI;
  float* gh     = ws + WS_GH;
  float* xm     = ws + WS_XM;
  float* hid    = ws + WS_HID;
  float* ata    = ws + WS_ATA;

  // stage 0: stats + gating + top-k + init
  hipMemsetAsync(ws, 0, WS_STATS_BYTES, stream);
  k_stats<<<B_ * 8, 256, 0, stream>>>(s, mu, Sigma, mask, ws);
  k_fin<<<1, 64, 0, stream>>>(ws);
  k_topk<<<B_, 256, 0, stream>>>(ws + WS_SSUM, gW, pool, idxi, idxf);
  k_init<<<B_ * KU_, 256, 0, stream>>>(idxi, pool, geop, ws, slots, muk, sigk);

  // k_sem = s @ proj_k_W.T
  k_gemm<8, 1, false, false, false><<<(B_ * N_) / 8, 256, 8 * C_ * 4, stream>>>(
      s, kW, nullptr, ksem, B_ * N_, C_, C_);

  const int RBK = (B_ * KU_ + 7) / 8;  // 86
  for (int it = 0; it < ITERS_; ++it) {
    k_gemm<8, 1, false, false, false><<<RBK, 256, 8 * C_ * 4, stream>>>(
        slots, qW, nullptr, qsem, B_ * KU_, C_, C_);
    k_logits<<<B_ * (N_ / 16), 256, 0, stream>>>(ksem, qsem, A);
    k_geosm<<<B_ * (N_ / 32), 256, 0, stream>>>(mu, Sigma, mask, muk, sigk, wgeo, gsr, gbias, A);
    k_accum1<<<B_ * KU_, 256, 0, stream>>>(A, mu, occ, muk);
    k_accum2<<<B_ * KU_, 256, 0, stream>>>(A, mu, Sigma, occ, muk, sigk);
    hipMemsetAsync(slotin, 0, (size_t)B_ * KU_ * C_ * 4, stream);
    k_atn<<<B_ * 11 * 8, 256, 0, stream>>>(A, s, slotin, C_);
    k_slotdiv<<<B_ * KU_, 256, 0, stream>>>(occ, slotin);
    k_gemm<8, 3, true, false, false><<<RBK, 256, 8 * C_ * 4, stream>>>(
        slotin, wih, bih, gi, B_ * KU_, C_, 3 * C_);
    k_gemm<8, 3, true, false, false><<<RBK, 256, 8 * C_ * 4, stream>>>(
        slots, whh, bhh, gh, B_ * KU_, C_, 3 * C_);
    k_gru<<<B_ * KU_, 256, 0, stream>>>(gi, gh, slots);
    k_ln<<<B_ * KU_, 256, 0, stream>>>(slots, lng, lnb, xm);
    k_gemm<8, 4, true, false, true><<<RBK, 256, 8 * C_ * 4, stream>>>(
        xm, w1, b1, hid, B_ * KU_, C_, 4 * C_);
    k_gemm<8, 1, true, true, false><<<RBK, 256, 8 * 1024 * 4, stream>>>(
        hid, w2, b2, slots, B_ * KU_, 4 * C_, C_);
  }

  // losses
  hipMemsetAsync(ata, 0, (size_t)B_ * KU_ * KU_ * 4, stream);
  k_atn<<<B_ * 11 * 8, 256, 0, stream>>>(A, A, ata, KU_);
  k_hist<<<1, 256, 0, stream>>>(idxi, okl, oent);
  k_occmse<<<1, 256, 0, stream>>>(occ, oocc);
  k_col<<<1, 256, 0, stream>>>(ata, okl, oent, oocc, ocol, otot);
}

// Round 3
// 998.947 us; speedup vs baseline: 1.8117x; 1.4606x over previous
//
#include <hip/hip_runtime.h>
#include <math.h>

#define B_ 4
#define N_ 2048
#define C_ 256
#define KMAX_ 1024
#define KU_ 171
#define ITERS_ 3
#define H_ 4
#define EPS_ 1e-8f
#define SIGF_ 0.03f
#define JIT_ 1e-6f
#define LOGKMAX_ 6.93147180559945f

// ---------------- workspace layout (float offsets) ----------------
#define WS_CNT 0          // 4
#define WS_MUS 4          // 12
#define WS_MOS 16         // 24
#define WS_SGS 40         // 36
#define WS_COLACC 100     // 1 (zeroed by the stats memset)
#define WS_SSUM 128       // 1024
#define WS_STATS_BYTES (1152*4)
#define WS_MEAN 1152      // 12
#define WS_STD 1164       // 12
#define WS_SIGAVG 1176    // 36
#define WS_IDXI 1216      // 684 ints (pad to 1920)
#define WS_KSEM 1920                  // B*N*C = 2097152
#define WS_QSEM (WS_KSEM+2097152)     // 175104
#define WS_OCC  (WS_QSEM+175104)      // 684 (pad 704)
#define WS_SLOTIN (WS_OCC+704)        // 175104
#define WS_GI (WS_SLOTIN+175104)      // 525312
#define WS_GH (WS_GI+525312)          // 525312 (unused now)
#define WS_XM (WS_GH+525312)          // 175104 -> reused as NRM (1368)
#define WS_NRM WS_XM
#define WS_HID (WS_XM+175104)         // 700416
#define WS_ATA (WS_HID+700416)        // 116964

// ---------------- output layout (float offsets) ----------------
#define O_A 0
#define O_SLOTS 1400832
#define O_MUK   1575936
#define O_SIGK  1577988
#define O_IDX   1584144
#define O_KL    1584828
#define O_ENT   1584829
#define O_OCC   1584830
#define O_COL   1584831
#define O_TOT   1584832

__device__ __forceinline__ float wred(float v) {
  #pragma unroll
  for (int i = 32; i; i >>= 1) v += __shfl_xor(v, i);
  return v;
}

__device__ __forceinline__ float blk_red(float v, float* red, int t) {
  red[t] = v; __syncthreads();
  #pragma unroll
  for (int s = 128; s > 0; s >>= 1) {
    if (t < s) red[t] += red[t + s];
    __syncthreads();
  }
  float r = red[0]; __syncthreads();
  return r;
}

// ---- partial batch stats ----
__global__ __launch_bounds__(256) void k_stats(const float* __restrict__ s,
    const float* __restrict__ mu, const float* __restrict__ Sigma,
    const float* __restrict__ mask, float* __restrict__ ws) {
  int blk = blockIdx.x; int b = blk / 8; int nc = blk % 8; int t = threadIdx.x;
  int n = nc * 256 + t;
  float m = mask[b * N_ + n];
  const float* mun = mu + ((size_t)(b * N_ + n)) * 3;
  float m0 = mun[0], m1v = mun[1], m2 = mun[2];
  const float* sgn = Sigma + ((size_t)(b * N_ + n)) * 9;
  float sg[9];
  #pragma unroll
  for (int j = 0; j < 9; j++) sg[j] = sgn[j];
  __shared__ float red[256];
  float v;
  v = blk_red(m, red, t);           if (t == 0) atomicAdd(ws + WS_CNT + b, v);
  v = blk_red(m * m0, red, t);      if (t == 0) atomicAdd(ws + WS_MUS + b * 3 + 0, v);
  v = blk_red(m * m1v, red, t);     if (t == 0) atomicAdd(ws + WS_MUS + b * 3 + 1, v);
  v = blk_red(m * m2, red, t);      if (t == 0) atomicAdd(ws + WS_MUS + b * 3 + 2, v);
  v = blk_red(m * m0 * m0, red, t); if (t == 0) atomicAdd(ws + WS_MOS + b * 6 + 0, v);
  v = blk_red(m * m0 * m1v, red, t);if (t == 0) atomicAdd(ws + WS_MOS + b * 6 + 1, v);
  v = blk_red(m * m0 * m2, red, t); if (t == 0) atomicAdd(ws + WS_MOS + b * 6 + 2, v);
  v = blk_red(m * m1v * m1v, red, t);if (t == 0) atomicAdd(ws + WS_MOS + b * 6 + 3, v);
  v = blk_red(m * m1v * m2, red, t);if (t == 0) atomicAdd(ws + WS_MOS + b * 6 + 4, v);
  v = blk_red(m * m2 * m2, red, t); if (t == 0) atomicAdd(ws + WS_MOS + b * 6 + 5, v);
  #pragma unroll
  for (int j = 0; j < 9; j++) {
    v = blk_red(m * sg[j], red, t);
    if (t == 0) atomicAdd(ws + WS_SGS + b * 9 + j, v);
  }
  const float* sb = s + ((size_t)b * N_ + nc * 256) * C_;
  const float* mk = mask + b * N_ + nc * 256;
  float sa = 0.f;
  for (int nn = 0; nn < 256; nn++) sa += mk[nn] * sb[(size_t)nn * C_ + t];
  atomicAdd(ws + WS_SSUM + b * C_ + t, sa);
}

// ---- finalize mean/std/sigavg ----
__global__ __launch_bounds__(64) void k_fin(float* __restrict__ ws) {
  int t = threadIdx.x;
  if (t < B_) {
    int b = t;
    float cnt = fmaxf(ws[WS_CNT + b], EPS_);
    float me[3];
    #pragma unroll
    for (int i = 0; i < 3; i++) { me[i] = ws[WS_MUS + b * 3 + i] / cnt; ws[WS_MEAN + b * 3 + i] = me[i]; }
    const int dg[3] = {0, 3, 5};
    #pragma unroll
    for (int i = 0; i < 3; i++) {
      float cov = ws[WS_MOS + b * 6 + dg[i]] / cnt - me[i] * me[i];
      ws[WS_STD + b * 3 + i] = fmaxf(sqrtf(fmaxf(cov, EPS_)), SIGF_);
    }
    #pragma unroll
    for (int i = 0; i < 3; i++)
      #pragma unroll
      for (int j = 0; j < 3; j++)
        ws[WS_SIGAVG + b * 9 + i * 3 + j] =
            0.5f * (ws[WS_SGS + b * 9 + i * 3 + j] + ws[WS_SGS + b * 9 + j * 3 + i]) / cnt;
  }
}

// ---- gating + top-k via bitonic sort; order == jax.lax.top_k ----
__global__ __launch_bounds__(256) void k_topk(const float* __restrict__ ws_ssum,
    const float* __restrict__ gW, const float* __restrict__ pool,
    int* __restrict__ idx_o, float* __restrict__ idxf_o) {
  int b = blockIdx.x, t = threadIdx.x;
  __shared__ float sb[C_], qv[C_];
  __shared__ float val[KMAX_]; __shared__ int id[KMAX_];
  __shared__ float rv[256];
  sb[t] = ws_ssum[b * C_ + t];
  __syncthreads();
  float qr = 0.f;
  for (int c = 0; c < C_; c++) qr += sb[c] * gW[(size_t)t * C_ + c];
  float n2 = blk_red(qr * qr, rv, t);
  qv[t] = qr / fmaxf(sqrtf(n2), 1e-12f);
  __syncthreads();
  for (int j = t; j < KMAX_; j += 256) {
    float d = 0.f, p2 = 0.f;
    const float* pr = pool + (size_t)j * C_;
    for (int c = 0; c < C_; c++) { float pv = pr[c]; d += qv[c] * pv; p2 += pv * pv; }
    val[j] = d / fmaxf(sqrtf(p2), 1e-12f);
    id[j] = j;
  }
  __syncthreads();
  for (int kk = 2; kk <= KMAX_; kk <<= 1) {
    for (int j = kk >> 1; j > 0; j >>= 1) {
      for (int i = t; i < KMAX_; i += 256) {
        int ix = i ^ j;
        if (ix > i) {
          float va = val[i], vb = val[ix]; int ia = id[i], ib = id[ix];
          bool bBeforeA = (vb > va) || (vb == va && ib < ia);
          bool up = ((i & kk) == 0);
          if (up == bBeforeA) {
            val[i] = vb; val[ix] = va; id[i] = ib; id[ix] = ia;
          }
        }
      }
      __syncthreads();
    }
  }
  if (t < KU_) {
    idx_o[b * KU_ + t] = id[t];
    idxf_o[b * KU_ + t] = (float)id[t];
  }
}

// ---- init slots / mu_k / Sig_k ----
__global__ __launch_bounds__(256) void k_init(const int* __restrict__ idx,
    const float* __restrict__ pool, const float* __restrict__ geop,
    const float* __restrict__ ws, float* __restrict__ slots,
    float* __restrict__ mu_k, float* __restrict__ sig_k) {
  int blk = blockIdx.x; int b = blk / KU_, k = blk % KU_; int t = threadIdx.x;
  int j = idx[b * KU_ + k];
  slots[((size_t)(b * KU_ + k)) * C_ + t] = pool[(size_t)j * C_ + t];
  if (t < 3) {
    mu_k[(b * KU_ + k) * 3 + t] = ws[WS_MEAN + b * 3 + t] + geop[j * 3 + t] * (0.5f * ws[WS_STD + b * 3 + t]);
  }
  if (t < 9) {
    float v = ws[WS_SIGAVG + b * 9 + t] * 0.1f;
    if (t == 0 || t == 4 || t == 8) v += SIGF_ * SIGF_ + JIT_;
    sig_k[((size_t)(b * KU_ + k)) * 9 + t] = v;
  }
}

// ---- generic row GEMM, float4 operands, out-group tiling over blockIdx.y ----
// out[r, oc] = (ACC? out :0) + act( dot(stage(in[r,:]), W[oc,:]) + bias[oc] )
// DIVOCC: divide staged row by max(occ[r],1e-8). LNORM: per-row layernorm of stage (ROWS must be 4).
template<int ROWS, bool HASB, bool ACC, bool GELU_, bool DIVOCC, bool LNORM>
__global__ __launch_bounds__(256) void k_gemm(const float* __restrict__ in,
    const float* __restrict__ W, const float* __restrict__ bias,
    float* __restrict__ out, int IN, int OUT,
    const float* __restrict__ occ, const float* __restrict__ lng,
    const float* __restrict__ lnb) {
  extern __shared__ float sm[];
  __shared__ float lmean[4], lrstd[4];
  int t = threadIdx.x; int r0 = blockIdx.x * ROWS;
  int C4 = IN >> 2;
  for (int i = t; i < ROWS * C4; i += 256) {
    int rr = i / C4; int r = r0 + rr;
    float4 v = ((const float4*)(in + (size_t)r * IN))[i - rr * C4];
    if (DIVOCC) {
      float scv = 1.f / fmaxf(occ[r], 1e-8f);
      v.x *= scv; v.y *= scv; v.z *= scv; v.w *= scv;
    }
    ((float4*)sm)[i] = v;
  }
  __syncthreads();
  if (LNORM) {
    int w = t >> 6, lane = t & 63;
    float x0 = sm[w * 256 + lane], x1 = sm[w * 256 + lane + 64];
    float x2 = sm[w * 256 + lane + 128], x3 = sm[w * 256 + lane + 192];
    float mean = wred(x0 + x1 + x2 + x3) * (1.f / 256.f);
    float d0 = x0 - mean, d1 = x1 - mean, d2 = x2 - mean, d3 = x3 - mean;
    float var = wred(d0 * d0 + d1 * d1 + d2 * d2 + d3 * d3) * (1.f / 256.f);
    if (lane == 0) { lmean[w] = mean; lrstd[w] = rsqrtf(var + 1e-5f); }
    __syncthreads();
    for (int i = t; i < ROWS * 256; i += 256) {
      int rr = i >> 8; int c = i & 255;
      sm[i] = (sm[i] - lmean[rr]) * lrstd[rr] * lng[c] + lnb[c];
    }
    __syncthreads();
  }
  int oc = blockIdx.y * 256 + t;
  const float4* W4 = (const float4*)(W + (size_t)oc * IN);
  const float4* sm4 = (const float4*)sm;
  float acc[ROWS];
  #pragma unroll
  for (int a = 0; a < ROWS; a++) acc[a] = 0.f;
  for (int c4 = 0; c4 < C4; c4++) {
    float4 wv = W4[c4];
    #pragma unroll
    for (int a = 0; a < ROWS; a++) {
      float4 sv = sm4[a * C4 + c4];
      acc[a] += sv.x * wv.x + sv.y * wv.y + sv.z * wv.z + sv.w * wv.w;
    }
  }
  #pragma unroll
  for (int a = 0; a < ROWS; a++) {
    int r = r0 + a;
    float v = acc[a];
    if (HASB) v += bias[oc];
    if (GELU_) v = 0.5f * v * (1.0f + erff(v * 0.70710678118654752f));
    float* po = &out[(size_t)r * OUT + oc];
    if (ACC) *po += v; else *po = v;
  }
}

// ---- fused gh-gemm + GRU update; ROWS=4; writes slots in place ----
__global__ __launch_bounds__(256) void k_gruf(float* __restrict__ slots,
    const float* __restrict__ whh, const float* __restrict__ bhh,
    const float* __restrict__ gi) {
  __shared__ float sm[4 * C_];
  int t = threadIdx.x; int r0 = blockIdx.x * 4;
  for (int i = t; i < 4 * (C_ >> 2); i += 256) {
    int rr = i >> 6;
    ((float4*)sm)[i] = ((const float4*)(slots + (size_t)(r0 + rr) * C_))[i & 63];
  }
  __syncthreads();
  const float4* wr4 = (const float4*)(whh + (size_t)t * C_);
  const float4* wz4 = (const float4*)(whh + (size_t)(t + 256) * C_);
  const float4* wn4 = (const float4*)(whh + (size_t)(t + 512) * C_);
  const float4* sm4 = (const float4*)sm;
  float ar[4] = {0, 0, 0, 0}, az[4] = {0, 0, 0, 0}, an[4] = {0, 0, 0, 0};
  for (int c4 = 0; c4 < 64; c4++) {
    float4 wr = wr4[c4], wz = wz4[c4], wn = wn4[c4];
    #pragma unroll
    for (int a = 0; a < 4; a++) {
      float4 sv = sm4[a * 64 + c4];
      ar[a] += sv.x * wr.x + sv.y * wr.y + sv.z * wr.z + sv.w * wr.w;
      az[a] += sv.x * wz.x + sv.y * wz.y + sv.z * wz.z + sv.w * wz.w;
      an[a] += sv.x * wn.x + sv.y * wn.y + sv.z * wn.z + sv.w * wn.w;
    }
  }
  float br = bhh[t], bz = bhh[t + 256], bn = bhh[t + 512];
  #pragma unroll
  for (int a = 0; a < 4; a++) {
    int r = r0 + a;
    const float* gir = gi + (size_t)r * 768;
    float rg = 1.f / (1.f + expf(-(gir[t] + ar[a] + br)));
    float z = 1.f / (1.f + expf(-(gir[t + 256] + az[a] + bz)));
    float ng = tanhf(gir[t + 512] + rg * (an[a] + bn));
    float h = sm[a * C_ + t];
    slots[(size_t)r * C_ + t] = (1.f - z) * ng + z * h;
  }
}

// ---- logits_sem: A[b,n,k] = dot(k_sem[b,n,:], q_sem[b,k,:]) / 16 ----
__global__ __launch_bounds__(256) void k_logits(const float* __restrict__ ksem,
    const float* __restrict__ qsem, float* __restrict__ A) {
  int blk = blockIdx.x; int b = blk / (N_ / 16); int nt = blk % (N_ / 16); int t = threadIdx.x;
  __shared__ float sm[16 * C_];
  int r0 = nt * 16;
  for (int i = t; i < 16 * (C_ >> 2); i += 256) {
    int rr = i >> 6;
    ((float4*)sm)[i] = ((const float4*)(ksem + ((size_t)(b * N_ + r0 + rr)) * C_))[i & 63];
  }
  __syncthreads();
  if (t >= KU_) return;
  const float4* q4 = (const float4*)(qsem + ((size_t)(b * KU_ + t)) * C_);
  const float4* sm4 = (const float4*)sm;
  float acc[16];
  #pragma unroll
  for (int a = 0; a < 16; a++) acc[a] = 0.f;
  for (int c4 = 0; c4 < 64; c4++) {
    float4 qv = q4[c4];
    #pragma unroll
    for (int a = 0; a < 16; a++) {
      float4 sv = sm4[a * 64 + c4];
      acc[a] += sv.x * qv.x + sv.y * qv.y + sv.z * qv.z + sv.w * qv.w;
    }
  }
  #pragma unroll
  for (int a = 0; a < 16; a++)
    A[((size_t)(b * N_ + r0 + a)) * KU_ + t] = acc[a] * 0.0625f;
}

// ---- fused geo term + softmax, in-place on A; 8 threads per row ----
#define GS_CHUNK 22
__global__ __launch_bounds__(256) void k_geosm(const float* __restrict__ mu,
    const float* __restrict__ Sigma, const float* __restrict__ mask,
    const float* __restrict__ mu_k, const float* __restrict__ sig_k,
    const float* __restrict__ wgeo, const float* __restrict__ gsr,
    const float* __restrict__ gbias, float* __restrict__ A) {
  int blk = blockIdx.x;
  int b = blk / (N_ / 32); int nb = blk % (N_ / 32); int t = threadIdx.x;
  int rloc = t >> 3;
  int sub = t & 7;
  int n = nb * 32 + rloc;
  __shared__ float muk[KU_ * 3], sgk[KU_ * 6];
  for (int i = t; i < KU_ * 3; i += 256) muk[i] = mu_k[(size_t)b * KU_ * 3 + i];
  for (int i = t; i < KU_ * 6; i += 256) {
    int k = i / 6, c = i % 6;
    const int map[6] = {0, 1, 2, 4, 5, 8};
    sgk[i] = sig_k[((size_t)(b * KU_ + k)) * 9 + map[c]];
  }
  __syncthreads();
  float ah = 0.f, bs = 0.f;
  #pragma unroll
  for (int h = 0; h < H_; h++) {
    float x = gsr[h];
    ah += fmaxf(x, 0.f) + log1pf(expf(-fabsf(x)));
    bs += gbias[h];
  }
  float wg = wgeo[0];
  float m = mask[b * N_ + n];
  const float* mun = mu + ((size_t)(b * N_ + n)) * 3;
  const float* sgn = Sigma + ((size_t)(b * N_ + n)) * 9;
  float u0 = mun[0], u1 = mun[1], u2 = mun[2];
  float g00 = sgn[0], g01 = sgn[1], g02 = sgn[2], g11 = sgn[4], g12 = sgn[5], g22 = sgn[8];
  float* Arow = A + ((size_t)(b * N_ + n)) * KU_;
  const int k0 = sub * GS_CHUNK;
  float lv[GS_CHUNK];
  float mmax = -INFINITY;
  #pragma unroll
  for (int kk = 0; kk < GS_CHUNK; kk++) {
    int k = k0 + kk;
    float l = -INFINITY;
    if (k < KU_) {
      float d0 = u0 - muk[k * 3], d1 = u1 - muk[k * 3 + 1], d2 = u2 - muk[k * 3 + 2];
      float s00 = g00 + sgk[k * 6], s01 = g01 + sgk[k * 6 + 1], s02 = g02 + sgk[k * 6 + 2];
      float s11 = g11 + sgk[k * 6 + 3], s12 = g12 + sgk[k * 6 + 4], s22 = g22 + sgk[k * 6 + 5];
      float c00 = s11 * s22 - s12 * s12;
      float c01 = s02 * s12 - s01 * s22;
      float c02 = s01 * s12 - s02 * s11;
      float det = s00 * c00 + s01 * c01 + s02 * c02;
      float c11 = s00 * s22 - s02 * s02;
      float c12 = s01 * s02 - s00 * s12;
      float c22 = s00 * s11 - s01 * s01;
      float inv = 1.0f / det;
      float x0 = (c00 * d0 + c01 * d1 + c02 * d2) * inv;
      float x1 = (c01 * d0 + c11 * d1 + c12 * d2) * inv;
      float x2 = (c02 * d0 + c12 * d1 + c22 * d2) * inv;
      float maha = d0 * x0 + d1 * x1 + d2 * x2;
      float logdet = logf(fmaxf(det, 1e-30f));
      float G = -0.5f * (maha + logdet);
      l = Arow[k] + wg * (ah * G + bs);
      if (m < 0.5f) l = -1e9f;
    }
    lv[kk] = l;
    mmax = fmaxf(mmax, l);
  }
  mmax = fmaxf(mmax, __shfl_xor(mmax, 1));
  mmax = fmaxf(mmax, __shfl_xor(mmax, 2));
  mmax = fmaxf(mmax, __shfl_xor(mmax, 4));
  float ssum = 0.f;
  #pragma unroll
  for (int kk = 0; kk < GS_CHUNK; kk++) {
    float e = expf(lv[kk] - mmax);
    lv[kk] = e;
    ssum += e;
  }
  ssum += __shfl_xor(ssum, 1);
  ssum += __shfl_xor(ssum, 2);
  ssum += __shfl_xor(ssum, 4);
  float sc = m / ssum;
  #pragma unroll
  for (int kk = 0; kk < GS_CHUNK; kk++) {
    int k = k0 + kk;
    if (k < KU_) Arow[k] = lv[kk] * sc;
  }
}

// ---- fused occ + mu_k + Sig_k (single pass over A column, moment form) ----
__global__ __launch_bounds__(256) void k_accum(const float* __restrict__ A,
    const float* __restrict__ mu, const float* __restrict__ Sigma,
    float* __restrict__ occ, float* __restrict__ mu_k, float* __restrict__ sig_k) {
  int blk = blockIdx.x; int b = blk / KU_, k = blk % KU_; int t = threadIdx.x;
  float S0 = 0.f, S1x = 0.f, S1y = 0.f, S1z = 0.f;
  float M00 = 0.f, M01 = 0.f, M02 = 0.f, M11 = 0.f, M12 = 0.f, M22 = 0.f;
  for (int n = t; n < N_; n += 256) {
    float a = A[((size_t)(b * N_ + n)) * KU_ + k];
    const float* mr = mu + ((size_t)(b * N_ + n)) * 3;
    const float* sg = Sigma + ((size_t)(b * N_ + n)) * 9;
    float m0 = mr[0], m1 = mr[1], m2 = mr[2];
    S0 += a; S1x += a * m0; S1y += a * m1; S1z += a * m2;
    M00 += a * (sg[0] + m0 * m0); M01 += a * (sg[1] + m0 * m1); M02 += a * (sg[2] + m0 * m2);
    M11 += a * (sg[4] + m1 * m1); M12 += a * (sg[5] + m1 * m2); M22 += a * (sg[8] + m2 * m2);
  }
  __shared__ float part[10];
  if (t < 10) part[t] = 0.f;
  __syncthreads();
  float vals[10] = {S0, S1x, S1y, S1z, M00, M01, M02, M11, M12, M22};
  int lane = t & 63;
  #pragma unroll
  for (int i = 0; i < 10; i++) {
    float v = wred(vals[i]);
    if (lane == 0) atomicAdd(&part[i], v);
  }
  __syncthreads();
  if (t == 0) {
    float o = part[0];
    occ[b * KU_ + k] = o;
    float oc = fmaxf(o, EPS_);
    float s1x = part[1], s1y = part[2], s1z = part[3];
    float q0 = s1x / oc, q1 = s1y / oc, q2 = s1z / oc;
    mu_k[(b * KU_ + k) * 3 + 0] = q0;
    mu_k[(b * KU_ + k) * 3 + 1] = q1;
    mu_k[(b * KU_ + k) * 3 + 2] = q2;
    float v00 = (part[4] - 2.f * q0 * s1x + o * q0 * q0) / oc + JIT_;
    float v01 = (part[5] - q0 * s1y - s1x * q1 + o * q0 * q1) / oc;
    float v02 = (part[6] - q0 * s1z - s1x * q2 + o * q0 * q2) / oc;
    float v11 = (part[7] - 2.f * q1 * s1y + o * q1 * q1) / oc + JIT_;
    float v12 = (part[8] - q1 * s1z - s1y * q2 + o * q1 * q2) / oc;
    float v22 = (part[9] - 2.f * q2 * s1z + o * q2 * q2) / oc + JIT_;
    v00 = fmaxf(v00, SIGF_ * SIGF_) + JIT_;
    v11 = fmaxf(v11, SIGF_ * SIGF_) + JIT_;
    v22 = fmaxf(v22, SIGF_ * SIGF_) + JIT_;
    float* po = sig_k + ((size_t)(b * KU_ + k)) * 9;
    po[0] = v00; po[1] = v01; po[2] = v02;
    po[3] = v01; po[4] = v11; po[5] = v12;
    po[6] = v02; po[7] = v12; po[8] = v22;
  }
}

// ---- out[b,k,c] += sum_{n in chunk} A[b,n,k] * X[b,n,c] ----
__global__ __launch_bounds__(256) void k_atn(const float* __restrict__ A,
    const float* __restrict__ X, float* __restrict__ out, int NX) {
  int blk = blockIdx.x;
  int nc = blk & 7; int tmp = blk >> 3; int kt = tmp % 11; int b = tmp / 11;
  int t = threadIdx.x; int k0 = kt * 16;
  __shared__ float Ach[64 * 16];
  float acc[16];
  #pragma unroll
  for (int j = 0; j < 16; j++) acc[j] = 0.f;
  for (int n0 = nc * 256; n0 < nc * 256 + 256; n0 += 64) {
    __syncthreads();
    for (int i = t; i < 64 * 16; i += 256) {
      int nn = i >> 4, kk = i & 15; int k = k0 + kk;
      Ach[i] = (k < KU_) ? A[((size_t)(b * N_ + n0 + nn)) * KU_ + k] : 0.f;
    }
    __syncthreads();
    if (t < NX) {
      for (int nn = 0; nn < 64; nn++) {
        float xv = X[((size_t)(b * N_ + n0 + nn)) * NX + t];
        #pragma unroll
        for (int j = 0; j < 16; j++) acc[j] += Ach[(nn << 4) + j] * xv;
      }
    }
  }
  if (t < NX) {
    #pragma unroll
    for (int j = 0; j < 16; j++) {
      int k = k0 + j;
      if (k < KU_) atomicAdd(&out[((size_t)(b * KU_ + k)) * NX + t], acc[j]);
    }
  }
}

__global__ __launch_bounds__(256) void k_hist(const int* __restrict__ idx,
    float* __restrict__ okl, float* __restrict__ oent) {
  __shared__ float hist[KMAX_];
  int t = threadIdx.x;
  for (int i = t; i < KMAX_; i += 256) hist[i] = 0.f;
  __syncthreads();
  for (int i = t; i < B_ * KU_; i += 256) atomicAdd(&hist[idx[i]], 1.0f);
  __syncthreads();
  float kl = 0.f, ent = 0.f;
  const float tot = (float)(B_ * KU_);
  for (int i = t; i < KMAX_; i += 256) {
    float pc = fmaxf(hist[i] / tot, 1e-8f);
    float lp = logf(pc);
    kl += pc * (lp + LOGKMAX_);
    ent += pc * lp;
  }
  __shared__ float red[256];
  kl = blk_red(kl, red, t); ent = blk_red(ent, red, t);
  if (t == 0) { okl[0] = kl; oent[0] = ent; }
}

__global__ __launch_bounds__(256) void k_occmse(const float* __restrict__ occ,
    float* __restrict__ out) {
  __shared__ float so[B_ * KU_];
  int t = threadIdx.x;
  for (int i = t; i < B_ * KU_; i += 256) so[i] = occ[i];
  __syncthreads();
  __shared__ float red[256];
  __shared__ float bsum[B_];
  for (int b = 0; b < B_; b++) {
    float s = 0.f;
    for (int i = t; i < KU_; i += 256) s += so[b * KU_ + i];
    s = blk_red(s, red, t);
    if (t == 0) bsum[b] = fmaxf(s, 1e-8f);
    __syncthreads();
  }
  float acc = 0.f;
  const float invK = 1.0f / (float)KU_;
  for (int i = t; i < B_ * KU_; i += 256) {
    int b = i / KU_;
    float v = so[i] / bsum[b] - invK;
    acc += v * v;
  }
  acc = blk_red(acc, red, t);
  if (t == 0) out[0] = acc / (float)(B_ * KU_);
}

// ---- collapse loss: diag norms -> parallel partial -> finalize ----
__global__ __launch_bounds__(256) void k_coldiag(const float* __restrict__ AtA,
    float* __restrict__ nrm) {
  int i = blockIdx.x * 256 + threadIdx.x;
  if (i < B_ * KU_) {
    int k = i % KU_;
    nrm[i] = fmaxf(sqrtf(AtA[(size_t)i * KU_ + k]), 1e-8f);
  }
}

__global__ __launch_bounds__(256) void k_colpart(const float* __restrict__ AtA,
    const float* __restrict__ nrm, float* __restrict__ colacc) {
  int blk = blockIdx.x; int b = blk / KU_, k = blk % KU_; int t = threadIdx.x;
  float acc = 0.f;
  if (t < KU_ && t != k) {
    float v = AtA[((size_t)(b * KU_ + k)) * KU_ + t];
    float gm = v / (nrm[b * KU_ + k] * nrm[b * KU_ + t]);
    acc = gm * gm;
  }
  float v = wred(acc);
  __shared__ float p[4];
  if ((t & 63) == 0) p[t >> 6] = v;
  __syncthreads();
  if (t == 0) atomicAdd(colacc, p[0] + p[1] + p[2] + p[3]);
}

__global__ void k_colfin(const float* __restrict__ colacc,
    const float* __restrict__ okl, const float* __restrict__ oent,
    const float* __restrict__ oocc, float* __restrict__ ocol, float* __restrict__ otot) {
  float col = colacc[0] / (float)(B_ * KU_ * KU_);
  ocol[0] = col;
  otot[0] = 0.05f * okl[0] + 0.0f * oent[0] + 0.5f * oocc[0] + 0.1f * col;
}

extern "C" void kernel_launch(void* const* d_in, const int* in_sizes, int n_in,
                              void* d_out_v, int out_size, void* d_ws, size_t ws_size,
                              hipStream_t stream) {
  const float* s     = (const float*)d_in[0];
  const float* mu    = (const float*)d_in[1];
  const float* Sigma = (const float*)d_in[2];
  const float* mask  = (const float*)d_in[3];
  const float* pool  = (const float*)d_in[4];
  const float* geop  = (const float*)d_in[5];
  const float* gW    = (const float*)d_in[6];
  const float* qW    = (const float*)d_in[7];
  const float* kW    = (const float*)d_in[8];
  const float* wih   = (const float*)d_in[9];
  const float* whh   = (const float*)d_in[10];
  const float* bih   = (const float*)d_in[11];
  const float* bhh   = (const float*)d_in[12];
  const float* lng   = (const float*)d_in[13];
  const float* lnb   = (const float*)d_in[14];
  const float* w1    = (const float*)d_in[15];
  const float* b1    = (const float*)d_in[16];
  const float* w2    = (const float*)d_in[17];
  const float* b2    = (const float*)d_in[18];
  const float* wgeo  = (const float*)d_in[19];
  const float* gsr   = (const float*)d_in[20];
  const float* gbias = (const float*)d_in[21];

  float* out = (float*)d_out_v;
  float* A     = out + O_A;
  float* slots = out + O_SLOTS;
  float* muk   = out + O_MUK;
  float* sigk  = out + O_SIGK;
  float* idxf  = out + O_IDX;
  float* okl   = out + O_KL;
  float* oent  = out + O_ENT;
  float* oocc  = out + O_OCC;
  float* ocol  = out + O_COL;
  float* otot  = out + O_TOT;

  float* ws = (float*)d_ws;
  int*   idxi   = (int*)(ws + WS_IDXI);
  float* ksem   = ws + WS_KSEM;
  float* qsem   = ws + WS_QSEM;
  float* occ    = ws + WS_OCC;
  float* slotin = ws + WS_SLOTIN;
  float* gi     = ws + WS_GI;
  float* nrm    = ws + WS_NRM;
  float* hid    = ws + WS_HID;
  float* ata    = ws + WS_ATA;
  float* colacc = ws + WS_COLACC;

  // stage 0
  hipMemsetAsync(ws, 0, WS_STATS_BYTES, stream);
  k_stats<<<B_ * 8, 256, 0, stream>>>(s, mu, Sigma, mask, ws);
  k_fin<<<1, 64, 0, stream>>>(ws);
  k_topk<<<B_, 256, 0, stream>>>(ws + WS_SSUM, gW, pool, idxi, idxf);
  k_init<<<B_ * KU_, 256, 0, stream>>>(idxi, pool, geop, ws, slots, muk, sigk);

  // k_sem = s @ kW.T  (8192 rows)
  k_gemm<8, false, false, false, false, false><<<dim3(1024, 1), 256, 8 * C_ * 4, stream>>>(
      s, kW, nullptr, ksem, C_, C_, nullptr, nullptr, nullptr);

  for (int it = 0; it < ITERS_; ++it) {
    k_gemm<4, false, false, false, false, false><<<dim3(171, 1), 256, 4 * C_ * 4, stream>>>(
        slots, qW, nullptr, qsem, C_, C_, nullptr, nullptr, nullptr);
    k_logits<<<B_ * (N_ / 16), 256, 0, stream>>>(ksem, qsem, A);
    k_geosm<<<B_ * (N_ / 32), 256, 0, stream>>>(mu, Sigma, mask, muk, sigk, wgeo, gsr, gbias, A);
    k_accum<<<B_ * KU_, 256, 0, stream>>>(A, mu, Sigma, occ, muk, sigk);
    hipMemsetAsync(slotin, 0, (size_t)B_ * KU_ * C_ * 4, stream);
    k_atn<<<B_ * 11 * 8, 256, 0, stream>>>(A, s, slotin, C_);
    // gi = (slotin/occ) @ wih.T + bih
    k_gemm<4, true, false, false, true, false><<<dim3(171, 3), 256, 4 * C_ * 4, stream>>>(
        slotin, wih, bih, gi, C_, 3 * C_, occ, nullptr, nullptr);
    // gh gemm + GRU fused
    k_gruf<<<171, 256, 0, stream>>>(slots, whh, bhh, gi);
    // hid = gelu(LN(slots) @ w1.T + b1)
    k_gemm<4, true, false, true, false, true><<<dim3(171, 4), 256, 4 * C_ * 4, stream>>>(
        slots, w1, b1, hid, C_, 4 * C_, nullptr, lng, lnb);
    // slots += hid @ w2.T + b2
    k_gemm<4, true, true, false, false, false><<<dim3(171, 1), 256, 4 * 1024 * 4, stream>>>(
        hid, w2, b2, slots, 4 * C_, C_, nullptr, nullptr, nullptr);
  }

  // losses
  hipMemsetAsync(ata, 0, (size_t)B_ * KU_ * KU_ * 4, stream);
  k_atn<<<B_ * 11 * 8, 256, 0, stream>>>(A, A, ata, KU_);
  k_coldiag<<<6, 256, 0, stream>>>(ata, nrm);
  k_colpart<<<B_ * KU_, 256, 0, stream>>>(ata, nrm, colacc);
  k_hist<<<1, 256, 0, stream>>>(idxi, okl, oent);
  k_occmse<<<1, 256, 0, stream>>>(occ, oocc);
  k_colfin<<<1, 1, 0, stream>>>(colacc, okl, oent, oocc, ocol, otot);
}